// Round 7
// baseline (358.964 us; speedup 1.0000x reference)
//
#include <hip/hip_runtime.h>

#define NB 4
#define NC 256
#define NHW 4096
#define NW 64
#define NTOPK 100
#define FMARGIN 4.1f
#define EQCAP 256

typedef short s16x8 __attribute__((ext_vector_type(8)));
typedef float f32x4 __attribute__((ext_vector_type(4)));

__device__ __forceinline__ unsigned int tokey(float f) {
    unsigned int u = __float_as_uint(f);
    return (u & 0x80000000u) ? ~u : (u | 0x80000000u);
}
__device__ __forceinline__ float k16tof(unsigned int k) {
    unsigned int k32 = k << 16;
    return __uint_as_float((k32 & 0x80000000u) ? (k32 ^ 0x80000000u) : ~k32);
}
__device__ __forceinline__ unsigned short f2b(float f) {
    unsigned int u = __float_as_uint(f);
    return (unsigned short)((u + 0x7FFFu + ((u >> 16) & 1u)) >> 16);
}

// ---- inverse norms for sketch & ref vectors ----
__global__ void k_norms(const float* __restrict__ sk, const float* __restrict__ rf,
                        float* __restrict__ inv_sk, float* __restrict__ inv_rf) {
    int which = blockIdx.x >> 6;
    int rem = blockIdx.x & 63;
    int b = rem >> 4;
    int i = ((rem & 15) << 8) + threadIdx.x;
    const float* base = (which ? rf : sk) + (size_t)b * NC * NHW + i;
    float acc = 0.f;
    #pragma unroll 4
    for (int c = 0; c < NC; ++c) { float v = base[(size_t)c * NHW]; acc = fmaf(v, v, acc); }
    float inv = 1.0f / fmaxf(sqrtf(acc), 1e-8f);
    (which ? inv_rf : inv_sk)[b * NHW + i] = inv;
}

// ---- positive-pair (anchor) selection from the TPS grid ----
__global__ void k_anchor(const float* __restrict__ G, int* __restrict__ ac_flat,
                         int* __restrict__ pvalid) {
    int t = blockIdx.x * 256 + threadIdx.x;
    int b = t >> 12, p = t & (NHW - 1);
    float gxv = G[((size_t)b * NHW + p) * 2 + 0] * 64.0f;
    float gyv = G[((size_t)b * NHW + p) * 2 + 1] * 64.0f;
    float x0 = floorf(gxv), y0 = floorf(gyv);
    float cx[4] = {x0, x0 + 1.f, x0 + 1.f, x0};
    float cy[4] = {y0, y0, y0 + 1.f, y0 + 1.f};
    float d[4]; bool v[4]; float maxd = -INFINITY; bool any = false;
    #pragma unroll
    for (int i = 0; i < 4; ++i) {
        float dx = gxv - cx[i], dy = gyv - cy[i];
        d[i] = sqrtf(dx * dx + dy * dy);
        v[i] = (cx[i] >= 0.f) && (cy[i] >= 0.f) && (cx[i] <= 63.f) && (cy[i] <= 63.f);
        any = any || v[i];
        maxd = fmaxf(maxd, d[i]);
    }
    int sel = 0; float best = -INFINITY;
    #pragma unroll
    for (int i = 0; i < 4; ++i) {
        float prob = v[i] ? ((maxd + 0.3f) - d[i]) : -INFINITY;
        if (prob > best) { best = prob; sel = i; }
    }
    int acx = (int)cx[sel], acy = (int)cy[sel];
    int af = acy * NW + acx;
    af = af < 0 ? 0 : (af > NHW - 1 ? NHW - 1 : af);
    ac_flat[t] = af;
    pvalid[t] = any ? 1 : 0;
}

// ---- transpose+normalize sk -> skT[b][q][c] bf16 (coalesced anchor rows) ----
__global__ void k_packA(const float* __restrict__ sk, const float* __restrict__ inv_sk,
                        unsigned short* __restrict__ skT) {
    __shared__ unsigned short tile[64][NC + 8];
    const int blk = blockIdx.x;
    const int b = blk >> 6;
    const int q0 = (blk & 63) << 6;
    const int t = threadIdx.x;
    const int qloc = t & 63;
    const int c0 = t >> 6;
    const float iv = inv_sk[b * NHW + q0 + qloc];
    const float* base = sk + (size_t)b * NC * NHW + q0 + qloc;
    #pragma unroll 8
    for (int cc = 0; cc < NC; cc += 4) {
        int c = cc + c0;
        tile[qloc][c] = f2b(base[(size_t)c * NHW] * iv);
    }
    __syncthreads();
    const int row = t >> 2, seg = (t & 3) * 64;
    unsigned short* out = skT + ((size_t)b * NHW + q0 + row) * NC + seg;
    #pragma unroll
    for (int j = 0; j < 64; j += 8)
        *(s16x8*)(out + j) = *(const s16x8*)&tile[row][seg + j];
}

// ---- transpose+normalize rf -> packed MFMA B layout refP[b][qt][kt][lane][8] ----
__global__ void k_packB(const float* __restrict__ rf, const float* __restrict__ inv_rf,
                        unsigned short* __restrict__ refP) {
    __shared__ unsigned short tile[64][NC + 8];
    const int blk = blockIdx.x;
    const int b = blk >> 6;
    const int q0 = (blk & 63) << 6;
    const int t = threadIdx.x;
    const int qloc = t & 63;
    const int c0 = t >> 6;
    const float iv = inv_rf[b * NHW + q0 + qloc];
    const float* base = rf + (size_t)b * NC * NHW + q0 + qloc;
    #pragma unroll 8
    for (int cc = 0; cc < NC; cc += 4) {
        int c = cc + c0;
        tile[qloc][c] = f2b(base[(size_t)c * NHW] * iv);
    }
    __syncthreads();
    #pragma unroll
    for (int it = 0; it < 8; ++it) {
        int slot = it * 256 + t;            // 0..2047 = 4 qt x 8 kt x 64 lane
        int qt = slot >> 9;
        int kt = (slot >> 6) & 7;
        int lane = slot & 63;
        int g = lane >> 4, qll = lane & 15;
        int ql2 = (qt << 4) + qll;
        int c = kt * 32 + g * 8;
        size_t oidx = (((size_t)(b * 256 + (q0 >> 4) + qt) * 8 + kt) * 64 + lane) * 8;
        *(s16x8*)(refP + oidx) = *(const s16x8*)&tile[ql2][c];
    }
}

// ---- fused MFMA cos + 16-bit-key radix top-100 + filtered mean; 16 rows/block ----
// amdgpu_waves_per_eu(4,4): PIN the allocator at 4 waves/EU = 128 VGPR.
// launch_bounds(1024,4) alone only sets the MINIMUM; the allocator still
// targeted 8 waves/EU (64 VGPR) and spilled 40 B/thread (168 MB/dispatch).
template<int MODE>
__global__ __attribute__((amdgpu_flat_work_group_size(1024, 1024), amdgpu_waves_per_eu(4, 4)))
void k_main(
    const float* __restrict__ sk, const float* __restrict__ rf,
    const unsigned short* __restrict__ refP, const unsigned short* __restrict__ skT,
    const float* __restrict__ G,
    const float* __restrict__ inv_sk, const float* __restrict__ inv_rf,
    const int* __restrict__ ac_flat, const int* __restrict__ pvalid,
    float* __restrict__ row_val, int* __restrict__ row_valid)
{
    __shared__ __align__(16) unsigned short ancsA[8][64][8];   // A-frags, conflict-free
    __shared__ unsigned int hist[16][256];
    __shared__ unsigned int eqbuf[16][EQCAP];
    __shared__ unsigned int eqcnt[16];
    __shared__ float cpp[16], gxs[16], gys[16];
    __shared__ unsigned int kpre[16], kmask[16];
    __shared__ int kneed[16];
    __shared__ float rowsum[16];
    __shared__ int rowcnt[16];

    const int tid = threadIdx.x;
    const int lane = tid & 63;
    const int w = tid >> 6;
    const int g = lane >> 4;
    const int ql = lane & 15;
    // XCD-aware swizzle: each XCD's L2 keeps one half-batch panel resident
    const int lblk = (blockIdx.x & 7) * 128 + (blockIdx.x >> 3);
    const int b = lblk >> 8;
    const int p0 = (lblk & 255) << 4;

    // ---- phase A: anchors into ancsA[kk][lane(g,ql=row)][8] ----
    if constexpr (MODE == 2) {
        const int a = ac_flat[b * NHW + p0 + w];
        const unsigned short* src = skT + ((size_t)b * NHW + a) * NC;
        uint2 v = *(const uint2*)(src + lane * 4);   // 4 channels
        const int c = lane * 4;
        const int kk = c >> 5, gg = (c >> 3) & 3, j = c & 7;
        *(uint2*)&ancsA[kk][gg * 16 + w][j] = v;
    } else {
        const int a = ac_flat[b * NHW + p0 + w];
        const float iv = inv_sk[b * NHW + a];
        const float* sp = sk + (size_t)b * NC * NHW + a;
        const int c = lane * 4;
        unsigned short o[4];
        #pragma unroll
        for (int u = 0; u < 4; ++u) o[u] = f2b(sp[(size_t)(c + u) * NHW] * iv);
        const int kk = c >> 5, gg = (c >> 3) & 3, j = c & 7;
        *(uint2*)&ancsA[kk][gg * 16 + w][j] = *(uint2*)o;
    }
    if (tid < 16) {
        rowsum[tid] = 0.f; rowcnt[tid] = 0; eqcnt[tid] = 0u;
        kpre[tid] = 0u; kmask[tid] = 0u; kneed[tid] = NTOPK;
        float2 g2 = *(const float2*)&G[((size_t)b * NHW + p0 + tid) * 2];
        gxs[tid] = g2.x * 4096.f; gys[tid] = g2.y * 4096.f;
    }
    __syncthreads();

    // ---- phase B: tile-at-a-time MFMA, compress each tile to 16-bit keys ----
    // persistent state: keys[32] (u16 pairs); live acc: 4 regs only.
    unsigned int keys[32];
    const int wstar = p0 >> 8;
    const int tstar = (p0 >> 4) & 15;

    #pragma unroll
    for (int t = 0; t < 16; ++t) {
        f32x4 a4 = (f32x4){0.f, 0.f, 0.f, 0.f};
        if constexpr (MODE >= 1) {
            const unsigned short* bp =
                refP + (((size_t)(b * 256 + w * 16 + t) * 8) * 64 + lane) * 8;
            #pragma unroll
            for (int kk = 0; kk < 8; ++kk) {
                s16x8 af = *(const s16x8*)&ancsA[kk][lane][0];
                s16x8 bf = *(const s16x8*)(bp + (size_t)kk * 512);
                a4 = __builtin_amdgcn_mfma_f32_16x16x32_bf16(af, bf, a4, 0, 0, 0);
            }
        } else {
            const float* rp = rf + (size_t)b * NC * NHW;
            const int q = w * 256 + t * 16 + ql;
            const float ivq = inv_rf[b * NHW + q];
            #pragma unroll
            for (int kk = 0; kk < 8; ++kk) {
                s16x8 af = *(const s16x8*)&ancsA[kk][lane][0];
                unsigned short bfv[8];
                #pragma unroll
                for (int j = 0; j < 8; ++j)
                    bfv[j] = f2b(rp[(size_t)(kk * 32 + g * 8 + j) * NHW + q] * ivq);
                a4 = __builtin_amdgcn_mfma_f32_16x16x32_bf16(af, *(s16x8*)bfv, a4, 0, 0, 0);
            }
        }
        if (t == tstar && w == wstar) {     // diag capture (f32 exact), t compile-time
            #pragma unroll
            for (int i = 0; i < 4; ++i)
                if (ql == g * 4 + i) cpp[g * 4 + i] = a4[i];
        }
        keys[2 * t]     = (tokey(a4[0]) >> 16) | ((tokey(a4[1]) >> 16) << 16);
        keys[2 * t + 1] = (tokey(a4[2]) >> 16) | ((tokey(a4[3]) >> 16) << 16);
    }
    __syncthreads();

    // ---- phase C: 2-pass radix select over 16-bit keys ----
    for (int pass = 0; pass < 2; ++pass) {
        const int shift = 8 - 8 * pass;
        unsigned int* hf = &hist[0][0];
        hf[tid] = 0u; hf[tid + 1024] = 0u; hf[tid + 2048] = 0u; hf[tid + 3072] = 0u;
        __syncthreads();
        #pragma unroll
        for (int i = 0; i < 4; ++i) {
            const int r = g * 4 + i;
            const unsigned int pm = kmask[r], pp = kpre[r];
            #pragma unroll
            for (int t = 0; t < 16; ++t) {
                const unsigned int kk = (keys[2 * t + (i >> 1)] >> (16 * (i & 1))) & 0xFFFFu;
                if ((kk & pm) == pp) atomicAdd(&hist[r][(kk >> shift) & 255u], 1u);
            }
        }
        __syncthreads();
        {
            const int need = kneed[w];
            const unsigned int c0 = hist[w][lane * 4 + 0], c1 = hist[w][lane * 4 + 1],
                               c2 = hist[w][lane * 4 + 2], c3 = hist[w][lane * 4 + 3];
            int s = (int)(c0 + c1 + c2 + c3);
            int cum = s;
            #pragma unroll
            for (int d = 1; d < 64; d <<= 1) {
                int tt = __shfl_up(cum, d, 64);
                if (lane >= d) cum += tt;
            }
            const int cumex = cum - s;
            const bool crossed = (cumex < need) && (cum >= need);
            unsigned long long mk = __ballot(crossed);
            const int wlane = __ffsll(mk) - 1;
            if (lane == wlane) {
                int digit, below;
                if (cumex + (int)c0 >= need)                   { digit = lane * 4 + 0; below = cumex; }
                else if (cumex + (int)(c0 + c1) >= need)       { digit = lane * 4 + 1; below = cumex + (int)c0; }
                else if (cumex + (int)(c0 + c1 + c2) >= need)  { digit = lane * 4 + 2; below = cumex + (int)(c0 + c1); }
                else                                            { digit = lane * 4 + 3; below = cumex + (int)(c0 + c1 + c2); }
                kpre[w] |= ((unsigned)digit) << shift;
                kmask[w] |= 255u << shift;
                kneed[w] = need - below;
            }
        }
        __syncthreads();
    }

    // ---- phase D: strictly-below sum + tie candidates ----
    float psum[4] = {0.f, 0.f, 0.f, 0.f};
    int pcnt[4] = {0, 0, 0, 0};
    #pragma unroll
    for (int i = 0; i < 4; ++i) {
        const int r = g * 4 + i;
        const unsigned int Ks = kpre[r];
        const float dpos = 1.f - cpp[r];
        const int pg = p0 + r;
        const float px = gxs[r], py = gys[r];
        #pragma unroll
        for (int t = 0; t < 16; ++t) {
            const int q = w * 256 + t * 16 + ql;
            const unsigned int kk = (keys[2 * t + (i >> 1)] >> (16 * (i & 1))) & 0xFFFFu;
            if (kk < Ks) {
                bool keep = (q != pg);
                if (keep) {
                    float2 g2 = *(const float2*)&G[((size_t)b * NHW + q) * 2];
                    float dx = fabsf(g2.x * 4096.f - px), dy = fabsf(g2.y * 4096.f - py);
                    keep = !((dx < 1.2f) && (dy < 1.2f));
                }
                if (keep) {
                    float loss = fmaxf(dpos - (1.f - k16tof(kk)) + FMARGIN, 0.f);
                    psum[i] += loss; pcnt[i] += 1;
                }
            } else if (kk == Ks) {
                unsigned int ix = atomicAdd(&eqcnt[r], 1u);
                if (ix < EQCAP) eqbuf[r][ix] = (unsigned int)q;
            }
        }
    }
    #pragma unroll
    for (int i = 0; i < 4; ++i) {
        float s = psum[i]; int c = pcnt[i];
        #pragma unroll
        for (int d = 1; d < 16; d <<= 1) {
            s += __shfl_xor(s, d, 64);
            c += __shfl_xor(c, d, 64);
        }
        if (ql == 0) { atomicAdd(&rowsum[g * 4 + i], s); atomicAdd(&rowcnt[g * 4 + i], c); }
    }
    __syncthreads();

    // ---- finalize: wave w resolves row w's ties by smallest index ----
    {
        const int pg = p0 + w;
        const unsigned int Ks = kpre[w];
        const int tk = kneed[w];
        const int ecnt = min((int)eqcnt[w], EQCAP);
        const float dpos = 1.f - cpp[w];
        const float vstar = k16tof(Ks);
        const float px = gxs[w], py = gys[w];
        float es = 0.f; int ec = 0;
        for (int ix = lane; ix < ecnt; ix += 64) {
            const int q = (int)eqbuf[w][ix];
            int rank = 0;
            for (int t2 = 0; t2 < ecnt; ++t2) rank += (eqbuf[w][t2] < (unsigned)q) ? 1 : 0;
            if (rank < tk) {
                bool keep = (q != pg);
                if (keep) {
                    float2 g2 = *(const float2*)&G[((size_t)b * NHW + q) * 2];
                    float dx = fabsf(g2.x * 4096.f - px), dy = fabsf(g2.y * 4096.f - py);
                    keep = !((dx < 1.2f) && (dy < 1.2f));
                }
                if (keep) { es += fmaxf(dpos - (1.f - vstar) + FMARGIN, 0.f); ec += 1; }
            }
        }
        #pragma unroll
        for (int d = 1; d < 64; d <<= 1) {
            es += __shfl_xor(es, d, 64);
            ec += __shfl_xor(ec, d, 64);
        }
        if (lane == 0) {
            const float tot = rowsum[w] + es;
            const int cnt = rowcnt[w] + ec;
            const int pv = (pvalid[b * NHW + pg] != 0) && (cnt > 0);
            row_val[b * NHW + pg] = pv ? (tot / (float)cnt) : 0.f;
            row_valid[b * NHW + pg] = pv;
        }
    }
}

// ---- final deterministic reduction ----
__global__ void k_reduce(const float* __restrict__ row_val, const int* __restrict__ row_valid,
                         float* __restrict__ out) {
    __shared__ float ss[256];
    __shared__ int sc[256];
    float s = 0.f; int n = 0;
    for (int i = threadIdx.x; i < NB * NHW; i += 256) { s += row_val[i]; n += row_valid[i]; }
    ss[threadIdx.x] = s; sc[threadIdx.x] = n;
    __syncthreads();
    for (int d = 128; d > 0; d >>= 1) {
        if (threadIdx.x < d) { ss[threadIdx.x] += ss[threadIdx.x + d]; sc[threadIdx.x] += sc[threadIdx.x + d]; }
        __syncthreads();
    }
    if (threadIdx.x == 0) out[0] = ss[0] / (1e-6f + (float)sc[0]);
}

extern "C" void kernel_launch(void* const* d_in, const int* in_sizes, int n_in,
                              void* d_out, int out_size, void* d_ws, size_t ws_size,
                              hipStream_t stream) {
    const float* sk = (const float*)d_in[0];
    const float* rf = (const float*)d_in[1];
    const float* G  = (const float*)d_in[2];
    char* ws = (char*)d_ws;
    const size_t SMALL = 6ull * 65536ull;
    const size_t PANEL = (size_t)NB * NC * NHW * 2;   // 8 MB
    float* inv_sk = (float*)(ws + 0 * 65536);
    float* inv_rf = (float*)(ws + 1 * 65536);
    int*   ac     = (int*)  (ws + 2 * 65536);
    int*   pv     = (int*)  (ws + 3 * 65536);
    float* rv_    = (float*)(ws + 4 * 65536);
    int*   rvd    = (int*)  (ws + 5 * 65536);
    unsigned short* rf16 = (unsigned short*)(ws + SMALL);
    unsigned short* skT  = (unsigned short*)(ws + SMALL + PANEL);
    const int mode = (ws_size >= SMALL + 2 * PANEL) ? 2 : ((ws_size >= SMALL + PANEL) ? 1 : 0);

    hipLaunchKernelGGL(k_norms, dim3(128), dim3(256), 0, stream, sk, rf, inv_sk, inv_rf);
    hipLaunchKernelGGL(k_anchor, dim3(64), dim3(256), 0, stream, G, ac, pv);
    if (mode >= 1)
        hipLaunchKernelGGL(k_packB, dim3(256), dim3(256), 0, stream, rf, inv_rf, rf16);
    if (mode == 2)
        hipLaunchKernelGGL(k_packA, dim3(256), dim3(256), 0, stream, sk, inv_sk, skT);

    if (mode == 2)
        hipLaunchKernelGGL(HIP_KERNEL_NAME(k_main<2>), dim3(1024), dim3(1024), 0, stream,
                           sk, rf, rf16, skT, G, inv_sk, inv_rf, ac, pv, rv_, rvd);
    else if (mode == 1)
        hipLaunchKernelGGL(HIP_KERNEL_NAME(k_main<1>), dim3(1024), dim3(1024), 0, stream,
                           sk, rf, rf16, (const unsigned short*)nullptr, G, inv_sk, inv_rf, ac, pv, rv_, rvd);
    else
        hipLaunchKernelGGL(HIP_KERNEL_NAME(k_main<0>), dim3(1024), dim3(1024), 0, stream,
                           sk, rf, (const unsigned short*)nullptr, (const unsigned short*)nullptr,
                           G, inv_sk, inv_rf, ac, pv, rv_, rvd);
    hipLaunchKernelGGL(k_reduce, dim3(1), dim3(256), 0, stream, rv_, rvd, (float*)d_out);
}

// Round 8
// 293.058 us; speedup vs baseline: 1.2249x; 1.2249x over previous
//
#include <hip/hip_runtime.h>

#define NB 4
#define NC 256
#define NHW 4096
#define NW 64
#define NTOPK 100
#define FMARGIN 4.1f
#define EQCAP 128

typedef short s16x8 __attribute__((ext_vector_type(8)));
typedef float f32x4 __attribute__((ext_vector_type(4)));

__device__ __forceinline__ unsigned int tokey(float f) {
    unsigned int u = __float_as_uint(f);
    return (u & 0x80000000u) ? ~u : (u | 0x80000000u);
}
__device__ __forceinline__ float k16tof(unsigned int k) {
    unsigned int k32 = k << 16;
    return __uint_as_float((k32 & 0x80000000u) ? (k32 ^ 0x80000000u) : ~k32);
}
__device__ __forceinline__ unsigned short f2b(float f) {
    unsigned int u = __float_as_uint(f);
    return (unsigned short)((u + 0x7FFFu + ((u >> 16) & 1u)) >> 16);
}

// ---- inverse norms for sketch & ref vectors ----
__global__ void k_norms(const float* __restrict__ sk, const float* __restrict__ rf,
                        float* __restrict__ inv_sk, float* __restrict__ inv_rf) {
    int which = blockIdx.x >> 6;
    int rem = blockIdx.x & 63;
    int b = rem >> 4;
    int i = ((rem & 15) << 8) + threadIdx.x;
    const float* base = (which ? rf : sk) + (size_t)b * NC * NHW + i;
    float acc = 0.f;
    #pragma unroll 4
    for (int c = 0; c < NC; ++c) { float v = base[(size_t)c * NHW]; acc = fmaf(v, v, acc); }
    float inv = 1.0f / fmaxf(sqrtf(acc), 1e-8f);
    (which ? inv_rf : inv_sk)[b * NHW + i] = inv;
}

// ---- positive-pair (anchor) selection from the TPS grid ----
__global__ void k_anchor(const float* __restrict__ G, int* __restrict__ ac_flat,
                         int* __restrict__ pvalid) {
    int t = blockIdx.x * 256 + threadIdx.x;
    int b = t >> 12, p = t & (NHW - 1);
    float gxv = G[((size_t)b * NHW + p) * 2 + 0] * 64.0f;
    float gyv = G[((size_t)b * NHW + p) * 2 + 1] * 64.0f;
    float x0 = floorf(gxv), y0 = floorf(gyv);
    float cx[4] = {x0, x0 + 1.f, x0 + 1.f, x0};
    float cy[4] = {y0, y0, y0 + 1.f, y0 + 1.f};
    float d[4]; bool v[4]; float maxd = -INFINITY; bool any = false;
    #pragma unroll
    for (int i = 0; i < 4; ++i) {
        float dx = gxv - cx[i], dy = gyv - cy[i];
        d[i] = sqrtf(dx * dx + dy * dy);
        v[i] = (cx[i] >= 0.f) && (cy[i] >= 0.f) && (cx[i] <= 63.f) && (cy[i] <= 63.f);
        any = any || v[i];
        maxd = fmaxf(maxd, d[i]);
    }
    int sel = 0; float best = -INFINITY;
    #pragma unroll
    for (int i = 0; i < 4; ++i) {
        float prob = v[i] ? ((maxd + 0.3f) - d[i]) : -INFINITY;
        if (prob > best) { best = prob; sel = i; }
    }
    int acx = (int)cx[sel], acy = (int)cy[sel];
    int af = acy * NW + acx;
    af = af < 0 ? 0 : (af > NHW - 1 ? NHW - 1 : af);
    ac_flat[t] = af;
    pvalid[t] = any ? 1 : 0;
}

// ---- transpose+normalize sk -> skT[b][q][c] bf16 (coalesced anchor rows) ----
__global__ void k_packA(const float* __restrict__ sk, const float* __restrict__ inv_sk,
                        unsigned short* __restrict__ skT) {
    __shared__ unsigned short tile[64][NC + 8];
    const int blk = blockIdx.x;
    const int b = blk >> 6;
    const int q0 = (blk & 63) << 6;
    const int t = threadIdx.x;
    const int qloc = t & 63;
    const int c0 = t >> 6;
    const float iv = inv_sk[b * NHW + q0 + qloc];
    const float* base = sk + (size_t)b * NC * NHW + q0 + qloc;
    #pragma unroll 8
    for (int cc = 0; cc < NC; cc += 4) {
        int c = cc + c0;
        tile[qloc][c] = f2b(base[(size_t)c * NHW] * iv);
    }
    __syncthreads();
    const int row = t >> 2, seg = (t & 3) * 64;
    unsigned short* out = skT + ((size_t)b * NHW + q0 + row) * NC + seg;
    #pragma unroll
    for (int j = 0; j < 64; j += 8)
        *(s16x8*)(out + j) = *(const s16x8*)&tile[row][seg + j];
}

// ---- transpose+normalize rf -> packed MFMA B layout refP[b][qt][kt][lane][8] ----
__global__ void k_packB(const float* __restrict__ rf, const float* __restrict__ inv_rf,
                        unsigned short* __restrict__ refP) {
    __shared__ unsigned short tile[64][NC + 8];
    const int blk = blockIdx.x;
    const int b = blk >> 6;
    const int q0 = (blk & 63) << 6;
    const int t = threadIdx.x;
    const int qloc = t & 63;
    const int c0 = t >> 6;
    const float iv = inv_rf[b * NHW + q0 + qloc];
    const float* base = rf + (size_t)b * NC * NHW + q0 + qloc;
    #pragma unroll 8
    for (int cc = 0; cc < NC; cc += 4) {
        int c = cc + c0;
        tile[qloc][c] = f2b(base[(size_t)c * NHW] * iv);
    }
    __syncthreads();
    #pragma unroll
    for (int it = 0; it < 8; ++it) {
        int slot = it * 256 + t;            // 0..2047 = 4 qt x 8 kt x 64 lane
        int qt = slot >> 9;
        int kt = (slot >> 6) & 7;
        int lane = slot & 63;
        int g = lane >> 4, qll = lane & 15;
        int ql2 = (qt << 4) + qll;
        int c = kt * 32 + g * 8;
        size_t oidx = (((size_t)(b * 256 + (q0 >> 4) + qt) * 8 + kt) * 64 + lane) * 8;
        *(s16x8*)(refP + oidx) = *(const s16x8*)&tile[ql2][c];
    }
}

// ---- fused MFMA cos + 16-bit-key radix top-100 + filtered mean; 16 rows/block ----
// Keys live in LDS (cannot be demoted to scratch — rounds 2..7 all lost to
// private-array demotion: 168 MB/dispatch scratch traffic). hist unions with
// the anchor-fragment buffer (disjoint lifetimes). Total LDS ~156 KB -> 1
// block/CU = 16 waves = 4/SIMD (same occupancy as measured before).
template<int MODE>
__global__ __attribute__((amdgpu_flat_work_group_size(1024, 1024), amdgpu_waves_per_eu(4, 4)))
void k_main(
    const float* __restrict__ sk, const float* __restrict__ rf,
    const unsigned short* __restrict__ refP, const unsigned short* __restrict__ skT,
    const float* __restrict__ G,
    const float* __restrict__ inv_sk, const float* __restrict__ inv_rf,
    const int* __restrict__ ac_flat, const int* __restrict__ pvalid,
    float* __restrict__ row_val, int* __restrict__ row_valid)
{
    __shared__ unsigned short keysL[64][1024];      // 128 KB: [tile*4+reg][tid]
    __shared__ __align__(16) char ubuf[16 * 256 * 4]; // 16 KB union: ancsA | hist
    __shared__ unsigned int eqbuf[16][EQCAP];       // 8 KB
    __shared__ unsigned int eqcnt[16];
    __shared__ float cpp[16], gxs[16], gys[16];
    __shared__ unsigned int kpre[16], kmask[16];
    __shared__ int kneed[16];
    __shared__ float rowsum[16];
    __shared__ int rowcnt[16];

    auto ancsA = reinterpret_cast<unsigned short (*)[64][8]>(ubuf); // [8][64][8]
    auto hist  = reinterpret_cast<unsigned int (*)[256]>(ubuf);     // [16][256]

    const int tid = threadIdx.x;
    const int lane = tid & 63;
    const int w = tid >> 6;
    const int g = lane >> 4;
    const int ql = lane & 15;
    // XCD-aware swizzle: each XCD's L2 keeps one half-batch panel resident
    const int lblk = (blockIdx.x & 7) * 128 + (blockIdx.x >> 3);
    const int b = lblk >> 8;
    const int p0 = (lblk & 255) << 4;

    // ---- phase A: anchors into ancsA[kk][lane][8] ----
    if constexpr (MODE == 2) {
        const int a = ac_flat[b * NHW + p0 + w];
        const unsigned short* src = skT + ((size_t)b * NHW + a) * NC;
        uint2 v = *(const uint2*)(src + lane * 4);
        const int c = lane * 4;
        const int kk = c >> 5, gg = (c >> 3) & 3, j = c & 7;
        *(uint2*)&ancsA[kk][gg * 16 + w][j] = v;
    } else {
        const int a = ac_flat[b * NHW + p0 + w];
        const float iv = inv_sk[b * NHW + a];
        const float* sp = sk + (size_t)b * NC * NHW + a;
        const int c = lane * 4;
        unsigned short o0 = f2b(sp[(size_t)(c + 0) * NHW] * iv);
        unsigned short o1 = f2b(sp[(size_t)(c + 1) * NHW] * iv);
        unsigned short o2 = f2b(sp[(size_t)(c + 2) * NHW] * iv);
        unsigned short o3 = f2b(sp[(size_t)(c + 3) * NHW] * iv);
        const int kk = c >> 5, gg = (c >> 3) & 3, j = c & 7;
        ancsA[kk][gg * 16 + w][j + 0] = o0;
        ancsA[kk][gg * 16 + w][j + 1] = o1;
        ancsA[kk][gg * 16 + w][j + 2] = o2;
        ancsA[kk][gg * 16 + w][j + 3] = o3;
    }
    if (tid < 16) {
        rowsum[tid] = 0.f; rowcnt[tid] = 0; eqcnt[tid] = 0u;
        kpre[tid] = 0u; kmask[tid] = 0u; kneed[tid] = NTOPK;
        float2 g2 = *(const float2*)&G[((size_t)b * NHW + p0 + tid) * 2];
        gxs[tid] = g2.x * 4096.f; gys[tid] = g2.y * 4096.f;
    }
    __syncthreads();

    // ---- phase B: tile-at-a-time MFMA; keys straight to LDS ----
    const int wstar = p0 >> 8;
    const int tstar = (p0 >> 4) & 15;

    // hoist the 8 A-fragments (reused by all 16 tiles)
    s16x8 af0 = *(const s16x8*)&ancsA[0][lane][0];
    s16x8 af1 = *(const s16x8*)&ancsA[1][lane][0];
    s16x8 af2 = *(const s16x8*)&ancsA[2][lane][0];
    s16x8 af3 = *(const s16x8*)&ancsA[3][lane][0];
    s16x8 af4 = *(const s16x8*)&ancsA[4][lane][0];
    s16x8 af5 = *(const s16x8*)&ancsA[5][lane][0];
    s16x8 af6 = *(const s16x8*)&ancsA[6][lane][0];
    s16x8 af7 = *(const s16x8*)&ancsA[7][lane][0];

    #pragma unroll 4
    for (int t = 0; t < 16; ++t) {
        f32x4 a4 = (f32x4){0.f, 0.f, 0.f, 0.f};
        if constexpr (MODE >= 1) {
            const unsigned short* bpt =
                refP + (((size_t)(b * 256 + w * 16 + t) * 8) * 64 + lane) * 8;
            a4 = __builtin_amdgcn_mfma_f32_16x16x32_bf16(af0, *(const s16x8*)(bpt + 0 * 512), a4, 0, 0, 0);
            a4 = __builtin_amdgcn_mfma_f32_16x16x32_bf16(af1, *(const s16x8*)(bpt + 1 * 512), a4, 0, 0, 0);
            a4 = __builtin_amdgcn_mfma_f32_16x16x32_bf16(af2, *(const s16x8*)(bpt + 2 * 512), a4, 0, 0, 0);
            a4 = __builtin_amdgcn_mfma_f32_16x16x32_bf16(af3, *(const s16x8*)(bpt + 3 * 512), a4, 0, 0, 0);
            a4 = __builtin_amdgcn_mfma_f32_16x16x32_bf16(af4, *(const s16x8*)(bpt + 4 * 512), a4, 0, 0, 0);
            a4 = __builtin_amdgcn_mfma_f32_16x16x32_bf16(af5, *(const s16x8*)(bpt + 5 * 512), a4, 0, 0, 0);
            a4 = __builtin_amdgcn_mfma_f32_16x16x32_bf16(af6, *(const s16x8*)(bpt + 6 * 512), a4, 0, 0, 0);
            a4 = __builtin_amdgcn_mfma_f32_16x16x32_bf16(af7, *(const s16x8*)(bpt + 7 * 512), a4, 0, 0, 0);
        } else {
            const float* rp = rf + (size_t)b * NC * NHW;
            const int q = w * 256 + t * 16 + ql;
            const float ivq = inv_rf[b * NHW + q];
            #pragma unroll
            for (int kk = 0; kk < 8; ++kk) {
                unsigned short bfv[8];
                #pragma unroll
                for (int j = 0; j < 8; ++j)
                    bfv[j] = f2b(rp[(size_t)(kk * 32 + g * 8 + j) * NHW + q] * ivq);
                s16x8 afx = *(const s16x8*)&ancsA[kk][lane][0];
                a4 = __builtin_amdgcn_mfma_f32_16x16x32_bf16(afx, *(s16x8*)bfv, a4, 0, 0, 0);
            }
        }
        if (w == wstar && t == tstar) {     // diag capture (f32 exact)
            #pragma unroll
            for (int i = 0; i < 4; ++i)
                if (ql == g * 4 + i) cpp[g * 4 + i] = a4[i];
        }
        keysL[4 * t + 0][tid] = (unsigned short)(tokey(a4[0]) >> 16);
        keysL[4 * t + 1][tid] = (unsigned short)(tokey(a4[1]) >> 16);
        keysL[4 * t + 2][tid] = (unsigned short)(tokey(a4[2]) >> 16);
        keysL[4 * t + 3][tid] = (unsigned short)(tokey(a4[3]) >> 16);
    }
    __syncthreads();   // ancsA dead from here; hist may overwrite ubuf

    // ---- phase C: 2-pass radix select over 16-bit keys ----
    for (int pass = 0; pass < 2; ++pass) {
        const int shift = 8 - 8 * pass;
        unsigned int* hf = reinterpret_cast<unsigned int*>(ubuf);
        hf[tid] = 0u; hf[tid + 1024] = 0u; hf[tid + 2048] = 0u; hf[tid + 3072] = 0u;
        __syncthreads();
        #pragma unroll
        for (int i = 0; i < 4; ++i) {
            const int r = g * 4 + i;
            const unsigned int pm = kmask[r], pp = kpre[r];
            #pragma unroll 4
            for (int t = 0; t < 16; ++t) {
                const unsigned int kk = keysL[4 * t + i][tid];
                if ((kk & pm) == pp) atomicAdd(&hist[r][(kk >> shift) & 255u], 1u);
            }
        }
        __syncthreads();
        {
            const int need = kneed[w];
            const unsigned int c0 = hist[w][lane * 4 + 0], c1 = hist[w][lane * 4 + 1],
                               c2 = hist[w][lane * 4 + 2], c3 = hist[w][lane * 4 + 3];
            int s = (int)(c0 + c1 + c2 + c3);
            int cum = s;
            #pragma unroll
            for (int d = 1; d < 64; d <<= 1) {
                int tt = __shfl_up(cum, d, 64);
                if (lane >= d) cum += tt;
            }
            const int cumex = cum - s;
            const bool crossed = (cumex < need) && (cum >= need);
            unsigned long long mk = __ballot(crossed);
            const int wlane = __ffsll(mk) - 1;
            if (lane == wlane) {
                int digit, below;
                if (cumex + (int)c0 >= need)                   { digit = lane * 4 + 0; below = cumex; }
                else if (cumex + (int)(c0 + c1) >= need)       { digit = lane * 4 + 1; below = cumex + (int)c0; }
                else if (cumex + (int)(c0 + c1 + c2) >= need)  { digit = lane * 4 + 2; below = cumex + (int)(c0 + c1); }
                else                                            { digit = lane * 4 + 3; below = cumex + (int)(c0 + c1 + c2); }
                kpre[w] |= ((unsigned)digit) << shift;
                kmask[w] |= 255u << shift;
                kneed[w] = need - below;
            }
        }
        __syncthreads();
    }

    // ---- phase D: strictly-below sum + tie candidates ----
    float psum0 = 0.f; int pcnt0 = 0;   // named per-reg accumulators (no arrays)
    float psum1 = 0.f; int pcnt1 = 0;
    float psum2 = 0.f; int pcnt2 = 0;
    float psum3 = 0.f; int pcnt3 = 0;
    #pragma unroll
    for (int i = 0; i < 4; ++i) {
        const int r = g * 4 + i;
        const unsigned int Ks = kpre[r];
        const float dpos = 1.f - cpp[r];
        const int pg = p0 + r;
        const float px = gxs[r], py = gys[r];
        float ps = 0.f; int pc = 0;
        #pragma unroll 4
        for (int t = 0; t < 16; ++t) {
            const int q = w * 256 + t * 16 + ql;
            const unsigned int kk = keysL[4 * t + i][tid];
            if (kk < Ks) {
                bool keep = (q != pg);
                if (keep) {
                    float2 g2 = *(const float2*)&G[((size_t)b * NHW + q) * 2];
                    float dx = fabsf(g2.x * 4096.f - px), dy = fabsf(g2.y * 4096.f - py);
                    keep = !((dx < 1.2f) && (dy < 1.2f));
                }
                if (keep) {
                    float loss = fmaxf(dpos - (1.f - k16tof(kk)) + FMARGIN, 0.f);
                    ps += loss; pc += 1;
                }
            } else if (kk == Ks) {
                unsigned int ix = atomicAdd(&eqcnt[r], 1u);
                if (ix < EQCAP) eqbuf[r][ix] = (unsigned int)q;
            }
        }
        if (i == 0) { psum0 = ps; pcnt0 = pc; }
        else if (i == 1) { psum1 = ps; pcnt1 = pc; }
        else if (i == 2) { psum2 = ps; pcnt2 = pc; }
        else { psum3 = ps; pcnt3 = pc; }
    }
    #pragma unroll
    for (int i = 0; i < 4; ++i) {
        float s = (i == 0) ? psum0 : (i == 1) ? psum1 : (i == 2) ? psum2 : psum3;
        int c = (i == 0) ? pcnt0 : (i == 1) ? pcnt1 : (i == 2) ? pcnt2 : pcnt3;
        #pragma unroll
        for (int d = 1; d < 16; d <<= 1) {
            s += __shfl_xor(s, d, 64);
            c += __shfl_xor(c, d, 64);
        }
        if (ql == 0) { atomicAdd(&rowsum[g * 4 + i], s); atomicAdd(&rowcnt[g * 4 + i], c); }
    }
    __syncthreads();

    // ---- finalize: wave w resolves row w's ties by smallest index ----
    {
        const int pg = p0 + w;
        const unsigned int Ks = kpre[w];
        const int tk = kneed[w];
        const int ecnt = min((int)eqcnt[w], EQCAP);
        const float dpos = 1.f - cpp[w];
        const float vstar = k16tof(Ks);
        const float px = gxs[w], py = gys[w];
        float es = 0.f; int ec = 0;
        for (int ix = lane; ix < ecnt; ix += 64) {
            const int q = (int)eqbuf[w][ix];
            int rank = 0;
            for (int t2 = 0; t2 < ecnt; ++t2) rank += (eqbuf[w][t2] < (unsigned)q) ? 1 : 0;
            if (rank < tk) {
                bool keep = (q != pg);
                if (keep) {
                    float2 g2 = *(const float2*)&G[((size_t)b * NHW + q) * 2];
                    float dx = fabsf(g2.x * 4096.f - px), dy = fabsf(g2.y * 4096.f - py);
                    keep = !((dx < 1.2f) && (dy < 1.2f));
                }
                if (keep) { es += fmaxf(dpos - (1.f - vstar) + FMARGIN, 0.f); ec += 1; }
            }
        }
        #pragma unroll
        for (int d = 1; d < 64; d <<= 1) {
            es += __shfl_xor(es, d, 64);
            ec += __shfl_xor(ec, d, 64);
        }
        if (lane == 0) {
            const float tot = rowsum[w] + es;
            const int cnt = rowcnt[w] + ec;
            const int pv = (pvalid[b * NHW + pg] != 0) && (cnt > 0);
            row_val[b * NHW + pg] = pv ? (tot / (float)cnt) : 0.f;
            row_valid[b * NHW + pg] = pv;
        }
    }
}

// ---- final deterministic reduction ----
__global__ void k_reduce(const float* __restrict__ row_val, const int* __restrict__ row_valid,
                         float* __restrict__ out) {
    __shared__ float ss[256];
    __shared__ int sc[256];
    float s = 0.f; int n = 0;
    for (int i = threadIdx.x; i < NB * NHW; i += 256) { s += row_val[i]; n += row_valid[i]; }
    ss[threadIdx.x] = s; sc[threadIdx.x] = n;
    __syncthreads();
    for (int d = 128; d > 0; d >>= 1) {
        if (threadIdx.x < d) { ss[threadIdx.x] += ss[threadIdx.x + d]; sc[threadIdx.x] += sc[threadIdx.x + d]; }
        __syncthreads();
    }
    if (threadIdx.x == 0) out[0] = ss[0] / (1e-6f + (float)sc[0]);
}

extern "C" void kernel_launch(void* const* d_in, const int* in_sizes, int n_in,
                              void* d_out, int out_size, void* d_ws, size_t ws_size,
                              hipStream_t stream) {
    const float* sk = (const float*)d_in[0];
    const float* rf = (const float*)d_in[1];
    const float* G  = (const float*)d_in[2];
    char* ws = (char*)d_ws;
    const size_t SMALL = 6ull * 65536ull;
    const size_t PANEL = (size_t)NB * NC * NHW * 2;   // 8 MB
    float* inv_sk = (float*)(ws + 0 * 65536);
    float* inv_rf = (float*)(ws + 1 * 65536);
    int*   ac     = (int*)  (ws + 2 * 65536);
    int*   pv     = (int*)  (ws + 3 * 65536);
    float* rv_    = (float*)(ws + 4 * 65536);
    int*   rvd    = (int*)  (ws + 5 * 65536);
    unsigned short* rf16 = (unsigned short*)(ws + SMALL);
    unsigned short* skT  = (unsigned short*)(ws + SMALL + PANEL);
    const int mode = (ws_size >= SMALL + 2 * PANEL) ? 2 : ((ws_size >= SMALL + PANEL) ? 1 : 0);

    hipLaunchKernelGGL(k_norms, dim3(128), dim3(256), 0, stream, sk, rf, inv_sk, inv_rf);
    hipLaunchKernelGGL(k_anchor, dim3(64), dim3(256), 0, stream, G, ac, pv);
    if (mode >= 1)
        hipLaunchKernelGGL(k_packB, dim3(256), dim3(256), 0, stream, rf, inv_rf, rf16);
    if (mode == 2)
        hipLaunchKernelGGL(k_packA, dim3(256), dim3(256), 0, stream, sk, inv_sk, skT);

    if (mode == 2)
        hipLaunchKernelGGL(HIP_KERNEL_NAME(k_main<2>), dim3(1024), dim3(1024), 0, stream,
                           sk, rf, rf16, skT, G, inv_sk, inv_rf, ac, pv, rv_, rvd);
    else if (mode == 1)
        hipLaunchKernelGGL(HIP_KERNEL_NAME(k_main<1>), dim3(1024), dim3(1024), 0, stream,
                           sk, rf, rf16, (const unsigned short*)nullptr, G, inv_sk, inv_rf, ac, pv, rv_, rvd);
    else
        hipLaunchKernelGGL(HIP_KERNEL_NAME(k_main<0>), dim3(1024), dim3(1024), 0, stream,
                           sk, rf, (const unsigned short*)nullptr, (const unsigned short*)nullptr,
                           G, inv_sk, inv_rf, ac, pv, rv_, rvd);
    hipLaunchKernelGGL(k_reduce, dim3(1), dim3(256), 0, stream, rv_, rvd, (float*)d_out);
}

// Round 9
// 270.600 us; speedup vs baseline: 1.3265x; 1.0830x over previous
//
#include <hip/hip_runtime.h>

#define NB 4
#define NC 256
#define NHW 4096
#define NW 64
#define NTOPK 100
#define FMARGIN 4.1f

typedef short s16x8 __attribute__((ext_vector_type(8)));
typedef float f32x4 __attribute__((ext_vector_type(4)));

__device__ __forceinline__ unsigned int tokey(float f) {
    unsigned int u = __float_as_uint(f);
    return (u & 0x80000000u) ? ~u : (u | 0x80000000u);
}
__device__ __forceinline__ float k16tof(unsigned int k) {
    unsigned int k32 = k << 16;
    return __uint_as_float((k32 & 0x80000000u) ? (k32 ^ 0x80000000u) : ~k32);
}
__device__ __forceinline__ unsigned short f2b(float f) {
    unsigned int u = __float_as_uint(f);
    return (unsigned short)((u + 0x7FFFu + ((u >> 16) & 1u)) >> 16);
}

// ---- positive-pair (anchor) selection from the TPS grid ----
__global__ void k_anchor(const float* __restrict__ G, int* __restrict__ ac_flat,
                         int* __restrict__ pvalid) {
    int t = blockIdx.x * 256 + threadIdx.x;
    int b = t >> 12, p = t & (NHW - 1);
    float gxv = G[((size_t)b * NHW + p) * 2 + 0] * 64.0f;
    float gyv = G[((size_t)b * NHW + p) * 2 + 1] * 64.0f;
    float x0 = floorf(gxv), y0 = floorf(gyv);
    float cx[4] = {x0, x0 + 1.f, x0 + 1.f, x0};
    float cy[4] = {y0, y0, y0 + 1.f, y0 + 1.f};
    float d[4]; bool v[4]; float maxd = -INFINITY; bool any = false;
    #pragma unroll
    for (int i = 0; i < 4; ++i) {
        float dx = gxv - cx[i], dy = gyv - cy[i];
        d[i] = sqrtf(dx * dx + dy * dy);
        v[i] = (cx[i] >= 0.f) && (cy[i] >= 0.f) && (cx[i] <= 63.f) && (cy[i] <= 63.f);
        any = any || v[i];
        maxd = fmaxf(maxd, d[i]);
    }
    int sel = 0; float best = -INFINITY;
    #pragma unroll
    for (int i = 0; i < 4; ++i) {
        float prob = v[i] ? ((maxd + 0.3f) - d[i]) : -INFINITY;
        if (prob > best) { best = prob; sel = i; }
    }
    int acx = (int)cx[sel], acy = (int)cy[sel];
    int af = acy * NW + acx;
    af = af < 0 ? 0 : (af > NHW - 1 ? NHW - 1 : af);
    ac_flat[t] = af;
    pvalid[t] = any ? 1 : 0;
}

// ---- fused norm + transpose: sk -> skT[b][q][c] bf16 ----
__global__ void k_packA(const float* __restrict__ sk, unsigned short* __restrict__ skT) {
    __shared__ float tile[64][NC + 1];
    __shared__ float psum[4][64];
    __shared__ float invs[64];
    const int blk = blockIdx.x;
    const int b = blk >> 6;
    const int q0 = (blk & 63) << 6;
    const int t = threadIdx.x;
    const int qloc = t & 63;
    const int c0 = t >> 6;
    const float* base = sk + (size_t)b * NC * NHW + q0 + qloc;
    #pragma unroll 8
    for (int cc = 0; cc < NC; cc += 4) {
        int c = cc + c0;
        tile[qloc][c] = base[(size_t)c * NHW];
    }
    __syncthreads();
    {
        float s = 0.f;
        #pragma unroll 8
        for (int j = 0; j < 64; ++j) { float v = tile[qloc][c0 * 64 + j]; s = fmaf(v, v, s); }
        psum[c0][qloc] = s;
    }
    __syncthreads();
    if (t < 64)
        invs[t] = 1.f / fmaxf(sqrtf(psum[0][t] + psum[1][t] + psum[2][t] + psum[3][t]), 1e-8f);
    __syncthreads();
    const int row = t >> 2, seg = (t & 3) * 64;
    const float iv = invs[row];
    unsigned short* out = skT + ((size_t)b * NHW + q0 + row) * NC + seg;
    #pragma unroll
    for (int j0 = 0; j0 < 64; j0 += 8) {
        unsigned short o[8];
        #pragma unroll
        for (int jj = 0; jj < 8; ++jj) o[jj] = f2b(tile[row][seg + j0 + jj] * iv);
        *(s16x8*)(out + j0) = *(s16x8*)o;
    }
}

// ---- fused norm + pack: rf -> MFMA B layout refP[b][qt][kt][lane][8] bf16 ----
__global__ void k_packB(const float* __restrict__ rf, unsigned short* __restrict__ refP) {
    __shared__ float tile[64][NC + 1];
    __shared__ float psum[4][64];
    __shared__ float invs[64];
    const int blk = blockIdx.x;
    const int b = blk >> 6;
    const int q0 = (blk & 63) << 6;
    const int t = threadIdx.x;
    const int qloc = t & 63;
    const int c0 = t >> 6;
    const float* base = rf + (size_t)b * NC * NHW + q0 + qloc;
    #pragma unroll 8
    for (int cc = 0; cc < NC; cc += 4) {
        int c = cc + c0;
        tile[qloc][c] = base[(size_t)c * NHW];
    }
    __syncthreads();
    {
        float s = 0.f;
        #pragma unroll 8
        for (int j = 0; j < 64; ++j) { float v = tile[qloc][c0 * 64 + j]; s = fmaf(v, v, s); }
        psum[c0][qloc] = s;
    }
    __syncthreads();
    if (t < 64)
        invs[t] = 1.f / fmaxf(sqrtf(psum[0][t] + psum[1][t] + psum[2][t] + psum[3][t]), 1e-8f);
    __syncthreads();
    #pragma unroll
    for (int it = 0; it < 8; ++it) {
        int slot = it * 256 + t;            // 0..2047 = 4 qt x 8 kt x 64 lane
        int qt = slot >> 9;
        int kt = (slot >> 6) & 7;
        int lane = slot & 63;
        int g = lane >> 4, qll = lane & 15;
        int ql2 = (qt << 4) + qll;
        int c = kt * 32 + g * 8;
        const float iv = invs[ql2];
        unsigned short o[8];
        #pragma unroll
        for (int j = 0; j < 8; ++j) o[j] = f2b(tile[ql2][c + j] * iv);
        size_t oidx = (((size_t)(b * 256 + (q0 >> 4) + qt) * 8 + kt) * 64 + lane) * 8;
        *(s16x8*)(refP + oidx) = *(s16x8*)o;
    }
}

// ---- fused MFMA cos + wave-local ballot-binary-search top-100 + filtered mean ----
// Selection is per-wave (wave w owns row w): no histogram, no LDS atomics,
// no scan, 2 barriers total. key2[rp][c] packs rows 2rp(lo)/2rp+1(hi); storage
// is 16B-slot swizzled (slot ^= readerLane&15) so reads are bank-conflict-free.
__global__ __attribute__((amdgpu_flat_work_group_size(1024, 1024), amdgpu_waves_per_eu(4, 4)))
void k_main(const unsigned short* __restrict__ refP, const unsigned short* __restrict__ skT,
            const float* __restrict__ G,
            const int* __restrict__ ac_flat, const int* __restrict__ pvalid,
            float* __restrict__ row_val, int* __restrict__ row_valid)
{
    __shared__ unsigned int key2[8][NHW];               // 128 KB
    __shared__ __align__(16) unsigned short ancsA[8][64][8]; // 8 KB
    __shared__ float cpp[16];

    const int tid = threadIdx.x;
    const int lane = tid & 63;
    const int w = tid >> 6;
    const int g = lane >> 4;
    const int ql = lane & 15;
    // XCD-aware swizzle for refP L2 locality
    const int lblk = (blockIdx.x & 7) * 128 + (blockIdx.x >> 3);
    const int b = lblk >> 8;
    const int p0 = (lblk & 255) << 4;

    // ---- phase A: anchors into ancsA[kk][lane][8] ----
    {
        const int a = ac_flat[b * NHW + p0 + w];
        const unsigned short* src = skT + ((size_t)b * NHW + a) * NC;
        uint2 v = *(const uint2*)(src + lane * 4);
        const int c = lane * 4;
        const int kk = c >> 5, gg = (c >> 3) & 3, j = c & 7;
        *(uint2*)&ancsA[kk][gg * 16 + w][j] = v;
    }
    __syncthreads();

    // ---- phase B: MFMA, keys straight to swizzled key2 ----
    const int wstar = p0 >> 8;
    const int tstar = (p0 >> 4) & 15;
    s16x8 af0 = *(const s16x8*)&ancsA[0][lane][0];
    s16x8 af1 = *(const s16x8*)&ancsA[1][lane][0];
    s16x8 af2 = *(const s16x8*)&ancsA[2][lane][0];
    s16x8 af3 = *(const s16x8*)&ancsA[3][lane][0];
    s16x8 af4 = *(const s16x8*)&ancsA[4][lane][0];
    s16x8 af5 = *(const s16x8*)&ancsA[5][lane][0];
    s16x8 af6 = *(const s16x8*)&ancsA[6][lane][0];
    s16x8 af7 = *(const s16x8*)&ancsA[7][lane][0];

    #pragma unroll 4
    for (int t = 0; t < 16; ++t) {
        f32x4 a4 = (f32x4){0.f, 0.f, 0.f, 0.f};
        const unsigned short* bpt =
            refP + (((size_t)(b * 256 + w * 16 + t) * 8) * 64 + lane) * 8;
        a4 = __builtin_amdgcn_mfma_f32_16x16x32_bf16(af0, *(const s16x8*)(bpt + 0 * 512), a4, 0, 0, 0);
        a4 = __builtin_amdgcn_mfma_f32_16x16x32_bf16(af1, *(const s16x8*)(bpt + 1 * 512), a4, 0, 0, 0);
        a4 = __builtin_amdgcn_mfma_f32_16x16x32_bf16(af2, *(const s16x8*)(bpt + 2 * 512), a4, 0, 0, 0);
        a4 = __builtin_amdgcn_mfma_f32_16x16x32_bf16(af3, *(const s16x8*)(bpt + 3 * 512), a4, 0, 0, 0);
        a4 = __builtin_amdgcn_mfma_f32_16x16x32_bf16(af4, *(const s16x8*)(bpt + 4 * 512), a4, 0, 0, 0);
        a4 = __builtin_amdgcn_mfma_f32_16x16x32_bf16(af5, *(const s16x8*)(bpt + 5 * 512), a4, 0, 0, 0);
        a4 = __builtin_amdgcn_mfma_f32_16x16x32_bf16(af6, *(const s16x8*)(bpt + 6 * 512), a4, 0, 0, 0);
        a4 = __builtin_amdgcn_mfma_f32_16x16x32_bf16(af7, *(const s16x8*)(bpt + 7 * 512), a4, 0, 0, 0);
        if (w == wstar && t == tstar) {     // diag capture (f32 exact)
            #pragma unroll
            for (int i = 0; i < 4; ++i)
                if (ql == g * 4 + i) cpp[g * 4 + i] = a4[i];
        }
        unsigned int k01 = (tokey(a4[0]) >> 16) | ((tokey(a4[1]) >> 16) << 16);
        unsigned int k23 = (tokey(a4[2]) >> 16) | ((tokey(a4[3]) >> 16) << 16);
        // logical col c = w*256 + t*16 + ql; reader lane l_r = c>>6; swizzled store
        const int l_r = (w << 2) + (t >> 2);
        const int ach = ((t & 3) << 2) + (ql >> 2);
        const int pidx = (l_r << 6) + ((ach ^ (l_r & 15)) << 2) + (ql & 3);
        key2[(g << 1) + 0][pidx] = k01;
        key2[(g << 1) + 1][pidx] = k23;
    }
    __syncthreads();

    // ---- wave-local selection: wave w owns row w ----
    const int rp = w >> 1;
    const int half = w & 1;
    unsigned int pk[32];   // 64 keys packed 2/u32, cols lane*64 + 2j, 2j+1 (all static idx)
    #pragma unroll
    for (int ach = 0; ach < 16; ++ach) {
        const uint4 v = *(const uint4*)&key2[rp][(lane << 6) + ((ach ^ (lane & 15)) << 2)];
        unsigned int kx = half ? (v.x >> 16) : (v.x & 0xFFFFu);
        unsigned int ky = half ? (v.y >> 16) : (v.y & 0xFFFFu);
        unsigned int kz = half ? (v.z >> 16) : (v.z & 0xFFFFu);
        unsigned int kw = half ? (v.w >> 16) : (v.w & 0xFFFFu);
        pk[2 * ach + 0] = kx | (ky << 16);
        pk[2 * ach + 1] = kz | (kw << 16);
    }

    // exact 100th-smallest key via ballot binary search (SGPR-uniform, no LDS)
    unsigned int Ks = 0;
    #pragma unroll 1
    for (int bit = 15; bit >= 0; --bit) {
        const unsigned int T = Ks | (1u << bit);
        int c = 0;
        #pragma unroll
        for (int j = 0; j < 32; ++j) {
            c += __popcll(__ballot((pk[j] & 0xFFFFu) < T));
            c += __popcll(__ballot((pk[j] >> 16) < T));
        }
        if (c < NTOPK) Ks = T;
    }
    int below = 0;
    #pragma unroll
    for (int j = 0; j < 32; ++j) {
        below += __popcll(__ballot((pk[j] & 0xFFFFu) < Ks));
        below += __popcll(__ballot((pk[j] >> 16) < Ks));
    }
    const int tk = NTOPK - below;

    // ---- scan: strictly-below kept (filtered); ties by ascending col ----
    const float dpos = 1.0f - cpp[w];
    const int pg = p0 + w;
    const float2 gp = *(const float2*)&G[((size_t)b * NHW + pg) * 2];
    const float px = gp.x * 4096.f, py = gp.y * 4096.f;
    const float base_add = dpos + (FMARGIN - 1.0f);

    float sumv = 0.f; int cnt = 0;
    unsigned long long tmask = 0ull; int ltc = 0;
    #pragma unroll
    for (int j = 0; j < 32; ++j) {
        #pragma unroll
        for (int h = 0; h < 2; ++h) {
            const unsigned int k = h ? (pk[j] >> 16) : (pk[j] & 0xFFFFu);
            const int q = (lane << 6) + 2 * j + h;
            if (k < Ks) {
                bool keep = (q != pg);
                if (keep) {
                    float2 g2 = *(const float2*)&G[((size_t)b * NHW + q) * 2];
                    float dx = fabsf(g2.x * 4096.f - px), dy = fabsf(g2.y * 4096.f - py);
                    keep = !((dx < 1.2f) && (dy < 1.2f));
                }
                if (keep) { sumv += k16tof(k); cnt++; }
            } else if (k == Ks) {
                tmask |= (1ull << (2 * j + h));
                ltc++;
            }
        }
    }
    // exclusive prefix of tie counts across lanes (cols ascend with lane, then slot)
    int pfx = ltc;
    #pragma unroll
    for (int d = 1; d < 64; d <<= 1) {
        int t2 = __shfl_up(pfx, d, 64);
        if (lane >= d) pfx += t2;
    }
    pfx -= ltc;
    int ek = 0;
    if (ltc > 0 && pfx < tk) {
        int m = 0;
        #pragma unroll
        for (int s = 0; s < 64; ++s) {
            if (tmask & (1ull << s)) {
                if (pfx + m < tk) {
                    const int q = (lane << 6) + s;
                    bool keep = (q != pg);
                    if (keep) {
                        float2 g2 = *(const float2*)&G[((size_t)b * NHW + q) * 2];
                        float dx = fabsf(g2.x * 4096.f - px), dy = fabsf(g2.y * 4096.f - py);
                        keep = !((dx < 1.2f) && (dy < 1.2f));
                    }
                    if (keep) ek++;
                }
                m++;
            }
        }
    }
    const float vstar = k16tof(Ks);
    float fl = sumv + (float)cnt * base_add + (float)ek * (base_add + vstar);
    int ccnt = cnt + ek;
    #pragma unroll
    for (int d = 1; d < 64; d <<= 1) {
        fl += __shfl_xor(fl, d, 64);
        ccnt += __shfl_xor(ccnt, d, 64);
    }
    if (lane == 0) {
        const int pv = (pvalid[b * NHW + pg] != 0) && (ccnt > 0);
        row_val[b * NHW + pg] = pv ? (fl / (float)ccnt) : 0.f;
        row_valid[b * NHW + pg] = pv;
    }
}

// ---- final deterministic reduction ----
__global__ void k_reduce(const float* __restrict__ row_val, const int* __restrict__ row_valid,
                         float* __restrict__ out) {
    __shared__ float ss[256];
    __shared__ int sc[256];
    float s = 0.f; int n = 0;
    for (int i = threadIdx.x; i < NB * NHW; i += 256) { s += row_val[i]; n += row_valid[i]; }
    ss[threadIdx.x] = s; sc[threadIdx.x] = n;
    __syncthreads();
    for (int d = 128; d > 0; d >>= 1) {
        if (threadIdx.x < d) { ss[threadIdx.x] += ss[threadIdx.x + d]; sc[threadIdx.x] += sc[threadIdx.x + d]; }
        __syncthreads();
    }
    if (threadIdx.x == 0) out[0] = ss[0] / (1e-6f + (float)sc[0]);
}

extern "C" void kernel_launch(void* const* d_in, const int* in_sizes, int n_in,
                              void* d_out, int out_size, void* d_ws, size_t ws_size,
                              hipStream_t stream) {
    const float* sk = (const float*)d_in[0];
    const float* rf = (const float*)d_in[1];
    const float* G  = (const float*)d_in[2];
    char* ws = (char*)d_ws;
    const size_t PANEL = (size_t)NB * NC * NHW * 2;   // 8 MB
    int*   ac  = (int*)  (ws + 0 * 65536);
    int*   pv  = (int*)  (ws + 1 * 65536);
    float* rv_ = (float*)(ws + 2 * 65536);
    int*   rvd = (int*)  (ws + 3 * 65536);
    unsigned short* rf16 = (unsigned short*)(ws + 4 * 65536);
    unsigned short* skT  = (unsigned short*)(ws + 4 * 65536 + PANEL);
    // ws_size has provided >= 17 MB every round (mode-2 path has always run)

    hipLaunchKernelGGL(k_anchor, dim3(64), dim3(256), 0, stream, G, ac, pv);
    hipLaunchKernelGGL(k_packB, dim3(256), dim3(256), 0, stream, rf, rf16);
    hipLaunchKernelGGL(k_packA, dim3(256), dim3(256), 0, stream, sk, skT);
    hipLaunchKernelGGL(k_main, dim3(1024), dim3(1024), 0, stream,
                       rf16, skT, G, ac, pv, rv_, rvd);
    hipLaunchKernelGGL(k_reduce, dim3(1), dim3(256), 0, stream, rv_, rvd, (float*)d_out);
}

// Round 10
// 260.712 us; speedup vs baseline: 1.3769x; 1.0379x over previous
//
#include <hip/hip_runtime.h>

#define NB 4
#define NC 256
#define NHW 4096
#define NW 64
#define NTOPK 100
#define FMARGIN 4.1f

typedef short s16x8 __attribute__((ext_vector_type(8)));
typedef float f32x4 __attribute__((ext_vector_type(4)));

__device__ __forceinline__ unsigned int tokey(float f) {
    unsigned int u = __float_as_uint(f);
    return (u & 0x80000000u) ? ~u : (u | 0x80000000u);
}
__device__ __forceinline__ float k16tof(unsigned int k) {
    unsigned int k32 = k << 16;
    return __uint_as_float((k32 & 0x80000000u) ? (k32 ^ 0x80000000u) : ~k32);
}
__device__ __forceinline__ unsigned short f2b(float f) {
    unsigned int u = __float_as_uint(f);
    return (unsigned short)((u + 0x7FFFu + ((u >> 16) & 1u)) >> 16);
}

// ---- positive-pair (anchor) selection from the TPS grid ----
__global__ void k_anchor(const float* __restrict__ G, int* __restrict__ ac_flat,
                         int* __restrict__ pvalid) {
    int t = blockIdx.x * 256 + threadIdx.x;
    int b = t >> 12, p = t & (NHW - 1);
    float gxv = G[((size_t)b * NHW + p) * 2 + 0] * 64.0f;
    float gyv = G[((size_t)b * NHW + p) * 2 + 1] * 64.0f;
    float x0 = floorf(gxv), y0 = floorf(gyv);
    float cx[4] = {x0, x0 + 1.f, x0 + 1.f, x0};
    float cy[4] = {y0, y0, y0 + 1.f, y0 + 1.f};
    float d[4]; bool v[4]; float maxd = -INFINITY; bool any = false;
    #pragma unroll
    for (int i = 0; i < 4; ++i) {
        float dx = gxv - cx[i], dy = gyv - cy[i];
        d[i] = sqrtf(dx * dx + dy * dy);
        v[i] = (cx[i] >= 0.f) && (cy[i] >= 0.f) && (cx[i] <= 63.f) && (cy[i] <= 63.f);
        any = any || v[i];
        maxd = fmaxf(maxd, d[i]);
    }
    int sel = 0; float best = -INFINITY;
    #pragma unroll
    for (int i = 0; i < 4; ++i) {
        float prob = v[i] ? ((maxd + 0.3f) - d[i]) : -INFINITY;
        if (prob > best) { best = prob; sel = i; }
    }
    int acx = (int)cx[sel], acy = (int)cy[sel];
    int af = acy * NW + acx;
    af = af < 0 ? 0 : (af > NHW - 1 ? NHW - 1 : af);
    ac_flat[t] = af;
    pvalid[t] = any ? 1 : 0;
}

// ---- fused norm + transpose: sk -> skT[b][q][c] bf16 ----
__global__ void k_packA(const float* __restrict__ sk, unsigned short* __restrict__ skT) {
    __shared__ float tile[64][NC + 1];
    __shared__ float psum[4][64];
    __shared__ float invs[64];
    const int blk = blockIdx.x;
    const int b = blk >> 6;
    const int q0 = (blk & 63) << 6;
    const int t = threadIdx.x;
    const int qloc = t & 63;
    const int c0 = t >> 6;
    const float* base = sk + (size_t)b * NC * NHW + q0 + qloc;
    #pragma unroll 8
    for (int cc = 0; cc < NC; cc += 4) {
        int c = cc + c0;
        tile[qloc][c] = base[(size_t)c * NHW];
    }
    __syncthreads();
    {
        float s = 0.f;
        #pragma unroll 8
        for (int j = 0; j < 64; ++j) { float v = tile[qloc][c0 * 64 + j]; s = fmaf(v, v, s); }
        psum[c0][qloc] = s;
    }
    __syncthreads();
    if (t < 64)
        invs[t] = 1.f / fmaxf(sqrtf(psum[0][t] + psum[1][t] + psum[2][t] + psum[3][t]), 1e-8f);
    __syncthreads();
    const int row = t >> 2, seg = (t & 3) * 64;
    const float iv = invs[row];
    unsigned short* out = skT + ((size_t)b * NHW + q0 + row) * NC + seg;
    #pragma unroll
    for (int j0 = 0; j0 < 64; j0 += 8) {
        unsigned short o[8];
        #pragma unroll
        for (int jj = 0; jj < 8; ++jj) o[jj] = f2b(tile[row][seg + j0 + jj] * iv);
        *(s16x8*)(out + j0) = *(s16x8*)o;
    }
}

// ---- fused norm + pack: rf -> MFMA B layout refP[b][qt][kt][lane][8] bf16 ----
__global__ void k_packB(const float* __restrict__ rf, unsigned short* __restrict__ refP) {
    __shared__ float tile[64][NC + 1];
    __shared__ float psum[4][64];
    __shared__ float invs[64];
    const int blk = blockIdx.x;
    const int b = blk >> 6;
    const int q0 = (blk & 63) << 6;
    const int t = threadIdx.x;
    const int qloc = t & 63;
    const int c0 = t >> 6;
    const float* base = rf + (size_t)b * NC * NHW + q0 + qloc;
    #pragma unroll 8
    for (int cc = 0; cc < NC; cc += 4) {
        int c = cc + c0;
        tile[qloc][c] = base[(size_t)c * NHW];
    }
    __syncthreads();
    {
        float s = 0.f;
        #pragma unroll 8
        for (int j = 0; j < 64; ++j) { float v = tile[qloc][c0 * 64 + j]; s = fmaf(v, v, s); }
        psum[c0][qloc] = s;
    }
    __syncthreads();
    if (t < 64)
        invs[t] = 1.f / fmaxf(sqrtf(psum[0][t] + psum[1][t] + psum[2][t] + psum[3][t]), 1e-8f);
    __syncthreads();
    #pragma unroll
    for (int it = 0; it < 8; ++it) {
        int slot = it * 256 + t;
        int qt = slot >> 9;
        int kt = (slot >> 6) & 7;
        int lane = slot & 63;
        int g = lane >> 4, qll = lane & 15;
        int ql2 = (qt << 4) + qll;
        int c = kt * 32 + g * 8;
        const float iv = invs[ql2];
        unsigned short o[8];
        #pragma unroll
        for (int j = 0; j < 8; ++j) o[j] = f2b(tile[ql2][c + j] * iv);
        size_t oidx = (((size_t)(b * 256 + (q0 >> 4) + qt) * 8 + kt) * 64 + lane) * 8;
        *(s16x8*)(refP + oidx) = *(s16x8*)o;
    }
}

// ---- fused MFMA cos + wave-local selection with pre-unpacked keys ----
__global__ __attribute__((amdgpu_flat_work_group_size(1024, 1024), amdgpu_waves_per_eu(4, 4)))
void k_main(const unsigned short* __restrict__ refP, const unsigned short* __restrict__ skT,
            const float* __restrict__ G,
            const int* __restrict__ ac_flat, const int* __restrict__ pvalid,
            float* __restrict__ row_val, int* __restrict__ row_valid)
{
    __shared__ unsigned int key2[8][NHW];               // 128 KB
    __shared__ __align__(16) unsigned short ancsA[8][64][8]; // 8 KB
    __shared__ float cpp[16];

    const int tid = threadIdx.x;
    const int lane = tid & 63;
    const int w = tid >> 6;
    const int g = lane >> 4;
    const int ql = lane & 15;
    const int lblk = (blockIdx.x & 7) * 128 + (blockIdx.x >> 3);
    const int b = lblk >> 8;
    const int p0 = (lblk & 255) << 4;

    // ---- phase A ----
    {
        const int a = ac_flat[b * NHW + p0 + w];
        const unsigned short* src = skT + ((size_t)b * NHW + a) * NC;
        uint2 v = *(const uint2*)(src + lane * 4);
        const int c = lane * 4;
        const int kk = c >> 5, gg = (c >> 3) & 3, j = c & 7;
        *(uint2*)&ancsA[kk][gg * 16 + w][j] = v;
    }
    __syncthreads();

    // ---- phase B: MFMA, keys to swizzled key2 ----
    const int wstar = p0 >> 8;
    const int tstar = (p0 >> 4) & 15;
    s16x8 af0 = *(const s16x8*)&ancsA[0][lane][0];
    s16x8 af1 = *(const s16x8*)&ancsA[1][lane][0];
    s16x8 af2 = *(const s16x8*)&ancsA[2][lane][0];
    s16x8 af3 = *(const s16x8*)&ancsA[3][lane][0];
    s16x8 af4 = *(const s16x8*)&ancsA[4][lane][0];
    s16x8 af5 = *(const s16x8*)&ancsA[5][lane][0];
    s16x8 af6 = *(const s16x8*)&ancsA[6][lane][0];
    s16x8 af7 = *(const s16x8*)&ancsA[7][lane][0];

    #pragma unroll 4
    for (int t = 0; t < 16; ++t) {
        f32x4 a4 = (f32x4){0.f, 0.f, 0.f, 0.f};
        const unsigned short* bpt =
            refP + (((size_t)(b * 256 + w * 16 + t) * 8) * 64 + lane) * 8;
        a4 = __builtin_amdgcn_mfma_f32_16x16x32_bf16(af0, *(const s16x8*)(bpt + 0 * 512), a4, 0, 0, 0);
        a4 = __builtin_amdgcn_mfma_f32_16x16x32_bf16(af1, *(const s16x8*)(bpt + 1 * 512), a4, 0, 0, 0);
        a4 = __builtin_amdgcn_mfma_f32_16x16x32_bf16(af2, *(const s16x8*)(bpt + 2 * 512), a4, 0, 0, 0);
        a4 = __builtin_amdgcn_mfma_f32_16x16x32_bf16(af3, *(const s16x8*)(bpt + 3 * 512), a4, 0, 0, 0);
        a4 = __builtin_amdgcn_mfma_f32_16x16x32_bf16(af4, *(const s16x8*)(bpt + 4 * 512), a4, 0, 0, 0);
        a4 = __builtin_amdgcn_mfma_f32_16x16x32_bf16(af5, *(const s16x8*)(bpt + 5 * 512), a4, 0, 0, 0);
        a4 = __builtin_amdgcn_mfma_f32_16x16x32_bf16(af6, *(const s16x8*)(bpt + 6 * 512), a4, 0, 0, 0);
        a4 = __builtin_amdgcn_mfma_f32_16x16x32_bf16(af7, *(const s16x8*)(bpt + 7 * 512), a4, 0, 0, 0);
        if (w == wstar && t == tstar) {
            #pragma unroll
            for (int i = 0; i < 4; ++i)
                if (ql == g * 4 + i) cpp[g * 4 + i] = a4[i];
        }
        unsigned int k01 = (tokey(a4[0]) >> 16) | ((tokey(a4[1]) >> 16) << 16);
        unsigned int k23 = (tokey(a4[2]) >> 16) | ((tokey(a4[3]) >> 16) << 16);
        const int l_r = (w << 2) + (t >> 2);
        const int ach = ((t & 3) << 2) + (ql >> 2);
        const int pidx = (l_r << 6) + ((ach ^ (l_r & 15)) << 2) + (ql & 3);
        key2[(g << 1) + 0][pidx] = k01;
        key2[(g << 1) + 1][pidx] = k23;
    }
    __syncthreads();

    // ---- wave-local selection: wave w owns row w ----
    // uint4 read at swizzled slot 'ach' returns cols {8ach+0..7} of the row
    // pair, packed (2s,2s+1) per u32; 'half' picks column parity.
    const int rp = w >> 1;
    const int half = w & 1;
    unsigned int ku[64];   // ku[4*ach+m] = key for col lane*64 + 8*ach + 2*m + half
    #pragma unroll
    for (int ach = 0; ach < 16; ++ach) {
        const uint4 v = *(const uint4*)&key2[rp][(lane << 6) + ((ach ^ (lane & 15)) << 2)];
        ku[4 * ach + 0] = half ? (v.x >> 16) : (v.x & 0xFFFFu);
        ku[4 * ach + 1] = half ? (v.y >> 16) : (v.y & 0xFFFFu);
        ku[4 * ach + 2] = half ? (v.z >> 16) : (v.z & 0xFFFFu);
        ku[4 * ach + 3] = half ? (v.w >> 16) : (v.w & 0xFFFFu);
    }

    // exact 100th-smallest key: ballot binary search over bits 14..0
    unsigned int Ks = 0x4000u;
    #pragma unroll 1
    for (int bit = 14; bit >= 0; --bit) {
        const unsigned int T = Ks | (1u << bit);
        int c = 0;
        #pragma unroll
        for (int j = 0; j < 64; ++j)
            c += __popcll(__ballot(ku[j] < T));
        if (c < NTOPK) Ks = T;
    }
    int below = 0;
    #pragma unroll
    for (int j = 0; j < 64; ++j)
        below += __popcll(__ballot(ku[j] < Ks));
    const int tk = NTOPK - below;

    // ---- scan: strictly-below kept (filtered); ties by ascending col ----
    const float dpos = 1.0f - cpp[w];
    const int pg = p0 + w;
    const float2 gp = *(const float2*)&G[((size_t)b * NHW + pg) * 2];
    const float px = gp.x * 4096.f, py = gp.y * 4096.f;
    const float base_add = dpos + (FMARGIN - 1.0f);

    float sumv = 0.f; int cnt = 0;
    unsigned long long tmask = 0ull; int ltc = 0;
    #pragma unroll
    for (int j = 0; j < 64; ++j) {
        const unsigned int k = ku[j];
        if (k < Ks) {
            const int q = (lane << 6) + 8 * (j >> 2) + 2 * (j & 3) + half;
            bool keep = (q != pg);
            if (keep) {
                float2 g2 = *(const float2*)&G[((size_t)b * NHW + q) * 2];
                float dx = fabsf(g2.x * 4096.f - px), dy = fabsf(g2.y * 4096.f - py);
                keep = !((dx < 1.2f) && (dy < 1.2f));
            }
            if (keep) { sumv += k16tof(k); cnt++; }
        } else if (k == Ks) {
            // tie-order key within lane: column ascending == (ach, m) ascending == j ascending
            tmask |= (1ull << j);
            ltc++;
        }
    }
    int pfx = ltc;
    #pragma unroll
    for (int d = 1; d < 64; d <<= 1) {
        int t2 = __shfl_up(pfx, d, 64);
        if (lane >= d) pfx += t2;
    }
    pfx -= ltc;
    int ek = 0;
    if (ltc > 0 && pfx < tk) {
        unsigned long long mm = tmask;
        int m = 0;
        while (mm) {
            const int j = __ffsll((unsigned long long)mm) - 1;
            mm &= mm - 1;
            if (pfx + m < tk) {
                const int q = (lane << 6) + 8 * (j >> 2) + 2 * (j & 3) + half;
                bool keep = (q != pg);
                if (keep) {
                    float2 g2 = *(const float2*)&G[((size_t)b * NHW + q) * 2];
                    float dx = fabsf(g2.x * 4096.f - px), dy = fabsf(g2.y * 4096.f - py);
                    keep = !((dx < 1.2f) && (dy < 1.2f));
                }
                if (keep) ek++;
            }
            m++;
        }
    }
    const float vstar = k16tof(Ks);
    float fl = sumv + (float)cnt * base_add + (float)ek * (base_add + vstar);
    int ccnt = cnt + ek;
    #pragma unroll
    for (int d = 1; d < 64; d <<= 1) {
        fl += __shfl_xor(fl, d, 64);
        ccnt += __shfl_xor(ccnt, d, 64);
    }
    if (lane == 0) {
        const int pv = (pvalid[b * NHW + pg] != 0) && (ccnt > 0);
        row_val[b * NHW + pg] = pv ? (fl / (float)ccnt) : 0.f;
        row_valid[b * NHW + pg] = pv;
    }
}

// ---- final deterministic reduction ----
__global__ void k_reduce(const float* __restrict__ row_val, const int* __restrict__ row_valid,
                         float* __restrict__ out) {
    __shared__ float ss[256];
    __shared__ int sc[256];
    float s = 0.f; int n = 0;
    for (int i = threadIdx.x; i < NB * NHW; i += 256) { s += row_val[i]; n += row_valid[i]; }
    ss[threadIdx.x] = s; sc[threadIdx.x] = n;
    __syncthreads();
    for (int d = 128; d > 0; d >>= 1) {
        if (threadIdx.x < d) { ss[threadIdx.x] += ss[threadIdx.x + d]; sc[threadIdx.x] += sc[threadIdx.x + d]; }
        __syncthreads();
    }
    if (threadIdx.x == 0) out[0] = ss[0] / (1e-6f + (float)sc[0]);
}

extern "C" void kernel_launch(void* const* d_in, const int* in_sizes, int n_in,
                              void* d_out, int out_size, void* d_ws, size_t ws_size,
                              hipStream_t stream) {
    const float* sk = (const float*)d_in[0];
    const float* rf = (const float*)d_in[1];
    const float* G  = (const float*)d_in[2];
    char* ws = (char*)d_ws;
    const size_t PANEL = (size_t)NB * NC * NHW * 2;   // 8 MB
    int*   ac  = (int*)  (ws + 0 * 65536);
    int*   pv  = (int*)  (ws + 1 * 65536);
    float* rv_ = (float*)(ws + 2 * 65536);
    int*   rvd = (int*)  (ws + 3 * 65536);
    unsigned short* rf16 = (unsigned short*)(ws + 4 * 65536);
    unsigned short* skT  = (unsigned short*)(ws + 4 * 65536 + PANEL);

    hipLaunchKernelGGL(k_anchor, dim3(64), dim3(256), 0, stream, G, ac, pv);
    hipLaunchKernelGGL(k_packB, dim3(256), dim3(256), 0, stream, rf, rf16);
    hipLaunchKernelGGL(k_packA, dim3(256), dim3(256), 0, stream, sk, skT);
    hipLaunchKernelGGL(k_main, dim3(1024), dim3(1024), 0, stream,
                       rf16, skT, G, ac, pv, rv_, rvd);
    hipLaunchKernelGGL(k_reduce, dim3(1), dim3(256), 0, stream, rv_, rvd, (float*)d_out);
}